// Round 19
// baseline (75.794 us; speedup 1.0000x reference)
//
#include <hip/hip_runtime.h>
#include <stdint.h>

// ---- problem constants ----
#define DHW         13824      // 24*24*24 spatial positions per (b,c,g) plane
#define NCH         32         // channels C
#define NG          24         // octahedral group order
#define KDIM        2304       // ORIGINAL GEMM K (32 ch * 72)
#define NHEAD       64
#define TP          16         // spatial positions per block
#define CHS         16         // channels per stage (2 stages)
#define FPC         64         // folded+padded features/channel (60 distinct + 4 pad)
#define KP2         2048       // padded folded K: 2 stages x 16 ch x 64
#define KS2         64         // padded K-steps total (KP2/32)
#define KPSTG       32         // K-steps per stage
#define KQ          8          // K-steps per wave per stage (32/4, exact)
#define KPE         1032       // LDS row pitch in bf16 elems (16*64 + 8 pad -> 4-bank skew)
#define TILES_PER_B 864        // DHW / TP
#define NTILES      1728       // B * TILES_PER_B
#define NITEMS      (NTILES * 2)       // 3456 (tile, stage) work items
#define GRIDP       1024       // persistent blocks (>= 3-4 blocks/CU residency)
#define OUTN        1769472    // B * NHEAD * DHW  (output floats)
#define PREPB       512        // init_all blocks doing prep_w work (131072/256)
#define FILLB       1728       // init_all blocks doing bias_fill work (OUTN/4/256)
#define WS_WBS      294912     // ws bytes reserved for swizzled W (uses 262,144)

typedef __attribute__((ext_vector_type(2))) float    f32x2;
typedef __attribute__((ext_vector_type(8))) short    s16x8;
typedef __attribute__((ext_vector_type(4))) float    f32x4;
typedef __attribute__((ext_vector_type(4))) uint32_t u32x4;

// ---- compile-time Cayley table of S4 (matches itertools.permutations order) ----
// t1-fold extras: t1h[h] = t1*h, rep[12] = representatives of tau1[h]==tau1[t1*h].
struct Tables { int cay[NG][NG]; int s1[NG]; int s2[NG]; int t1h[NG]; int rep[12]; };

constexpr Tables make_tables() {
    int perms[NG][4] = {};
    int n = 0;
    for (int a = 0; a < 4; ++a)
        for (int b = 0; b < 4; ++b) {
            if (b == a) continue;
            for (int c = 0; c < 4; ++c) {
                if (c == a || c == b) continue;
                int d = 6 - a - b - c;
                perms[n][0] = a; perms[n][1] = b; perms[n][2] = c; perms[n][3] = d;
                ++n;
            }
        }
    int si1 = 0, si2 = 0;
    for (int i = 0; i < NG; ++i) {
        if (perms[i][0] == 1 && perms[i][1] == 0 && perms[i][2] == 2 && perms[i][3] == 3) si1 = i;
        if (perms[i][0] == 1 && perms[i][1] == 2 && perms[i][2] == 3 && perms[i][3] == 0) si2 = i;
    }
    Tables t{};
    for (int p = 0; p < NG; ++p) {
        for (int q = 0; q < NG; ++q) {
            int c0 = perms[p][perms[q][0]];
            int c1 = perms[p][perms[q][1]];
            int c2 = perms[p][perms[q][2]];
            int c3 = perms[p][perms[q][3]];
            int r = 0;
            for (int i = 0; i < NG; ++i)
                if (perms[i][0] == c0 && perms[i][1] == c1 &&
                    perms[i][2] == c2 && perms[i][3] == c3) { r = i; break; }
            t.cay[p][q] = r;
        }
        t.s1[p] = t.cay[p][si1];
        t.s2[p] = t.cay[p][si2];
    }
    for (int h = 0; h < NG; ++h) t.t1h[h] = t.cay[si1][h];   // t1 o h
    int nr = 0;
    for (int h = 0; h < NG; ++h) if (h < t.t1h[h]) t.rep[nr++] = h;   // 12 pairs
    return t;
}
constexpr Tables TAB = make_tables();

__device__ __forceinline__ uint32_t f2bf(float f) {   // fp32 -> bf16 (RNE), u16 in low bits
    uint32_t u = __float_as_uint(f);
    u += 0x7fffu + ((u >> 16) & 1u);
    return u >> 16;
}

// ---- kernel 1: merged init -- blocks [0,PREPB) fold+swizzle W; blocks [PREPB,..)
// pre-fill y with the bias pattern; block 0 thread 0 also zeroes the work-queue
// counter (R19). Branches are block-uniform.
// Folded feature order per channel: [0,24): tau0 | [24,36): tau1 reps (pair-summed W) |
// [36,60): tau2 | [60,64): zero pad. ln2 folded in (phase A uses log2).
__global__ __launch_bounds__(256) void init_all(const float* __restrict__ W,
                                                unsigned short* __restrict__ WbS,
                                                const float* __restrict__ bias,
                                                float* __restrict__ y,
                                                unsigned* __restrict__ qcnt) {
    const int blk = blockIdx.x;
    if (blk == 0 && threadIdx.x == 0) *qcnt = 0u;
    if (blk < PREPB) {
        int i = blk * 256 + threadIdx.x;             // < 64*2048 = 131072
        int j  = i & 7;
        int t1_ = i >> 3;
        int l  = t1_ & 63;
        int t2_ = t1_ >> 6;
        int kk = t2_ & (KS2 - 1);
        int ot = t2_ >> 6;
        int o = ot * 16 + (l & 15);
        int k = kk * 32 + ((l >> 4) << 3) + j;       // 0..2047 folded-K column
        int stage = k >> 10;                         // 0..1
        int q     = k & 1023;
        int c = stage * CHS + (q >> 6);              // channel
        int f = q & 63;                              // folded feature index
        const float* Wo = W + o * KDIM + c * 72;
        float val = 0.f;
        if (f < 24)      val = Wo[f * 3 + 0];
        else if (f < 36) { int h = TAB.rep[f - 24];
                           val = Wo[h * 3 + 1] + Wo[TAB.t1h[h] * 3 + 1]; }
        else if (f < 60) { int h = f - 36;          val = Wo[h * 3 + 2]; }
        WbS[i] = (unsigned short)f2bf(val * 0.69314718055994531f);
    } else {
        const int i4 = (blk - PREPB) * 256 + threadIdx.x;   // float4 index, OUTN%1024==0
        const float b = bias[((i4 * 4) / DHW) & (NHEAD - 1)];
        f32x4 v; v[0] = b; v[1] = b; v[2] = b; v[3] = b;
        ((f32x4*)y)[i4] = v;
    }
}

// ---- kernel 2: PERSISTENT fused bispectrum + log-feature + 64-head GEMM.
// R18's proven math/structure per item, wrapped in a work-queue loop (R19):
// 1024 persistent blocks grab (tile, 16-ch stage) items via global atomicAdd;
// the NEXT item's 24 x-loads are issued right after the current item's features
// hit LDS, overlapping phase B + epilogue (T14 async-split: latency-bound with a
// long compute phase to hide under). Queue also removes inter-block drain bubbles
// and self-balances CUs. launch_bounds(256,2): only healthy allocator surface.
__global__ __launch_bounds__(256, 2)
void bispec_fused(
        const float* __restrict__ x,
        const unsigned short* __restrict__ WbS,
        float* __restrict__ y,            // bias-prefilled output, atomic accumulate
        unsigned* __restrict__ qcnt)
{
    __shared__ alignas(16) unsigned short featS[TP * KPE];   // 33,024 B
    __shared__ unsigned sIdx;

    const int tid = threadIdx.x;
    const int p0 = tid & 15;          // position within tile (phase A)
    const int cl = tid >> 4;          // local channel 0..15 (phase A)
    const int w  = tid >> 6;          // wave: k-quarter in phase B, o-tile in epilogue
    const int l  = tid & 63;
    const int ln = l & 15;            // position col (phase B)
    const int lh = l >> 4;            // k sub-block (phase B)

    // ---- grab first item ----
    if (tid == 0) sIdx = atomicAdd(qcnt, 1u);
    __syncthreads();
    unsigned item = sIdx;
    if (item >= NITEMS) return;       // block-uniform exit

    // decode + initial x-load (exposed only once per block)
    unsigned tile  = item % NTILES;
    unsigned stage = item / NTILES;
    unsigned bb  = tile / TILES_PER_B;
    unsigned psp = (tile - bb * TILES_PER_B) * TP;
    float xf[NG];
    {
        const unsigned idx0 = (bb * NCH + stage * CHS + (unsigned)cl) * (NG * DHW)
                            + (psp + (unsigned)p0);
        #pragma unroll
        for (int g = 0; g < NG; ++g) xf[g] = x[idx0 + (unsigned)(g * DHW)];
    }

    for (;;) {
        const unsigned cur_bb = bb, cur_psp = psp, cur_stage = stage;

        // ---------------- phase A: tau core + log-feature on xf ----------------
        {
            f32x2 tau02[NG];         // (tau0, tau2) packed
            float tau1[12];          // 12 distinct s1 values (t1-fold)
            #pragma unroll
            for (int h = 0; h < NG; ++h) tau02[h] = (f32x2){0.f, 0.f};
            #pragma unroll
            for (int r = 0; r < 12; ++r) tau1[r] = 0.f;
            #pragma unroll
            for (int g = 0; g < NG; ++g) {
                const float xg = xf[g];
                const f32x2 q02 = (f32x2){xg, xg} * (f32x2){xg, xf[TAB.s2[g]]};
                const float q1 = xg * xf[TAB.s1[g]];
                #pragma unroll
                for (int h = 0; h < NG; ++h) {
                    const float v = xf[TAB.cay[g][h]];   // static register index
                    tau02[h] = __builtin_elementwise_fma((f32x2){v, v}, q02, tau02[h]);
                }
                #pragma unroll
                for (int r = 0; r < 12; ++r) {
                    const float v = xf[TAB.cay[g][TAB.rep[r]]];   // static register index
                    tau1[r] = fmaf(q1, v, tau1[r]);
                }
            }
            // feature = log2(1 + max(tau,0))  [ln2 folded into W]
            uint32_t pk[FPC / 2];
            #pragma unroll
            for (int i = 0; i < 12; ++i) {        // f 0..23: tau0
                float a = __log2f(1.f + fmaxf(tau02[2*i][0],   0.f));
                float b = __log2f(1.f + fmaxf(tau02[2*i+1][0], 0.f));
                pk[i] = f2bf(a) | (f2bf(b) << 16);
            }
            #pragma unroll
            for (int i = 0; i < 6; ++i) {         // f 24..35: tau1 reps
                float a = __log2f(1.f + fmaxf(tau1[2*i],   0.f));
                float b = __log2f(1.f + fmaxf(tau1[2*i+1], 0.f));
                pk[12 + i] = f2bf(a) | (f2bf(b) << 16);
            }
            #pragma unroll
            for (int i = 0; i < 12; ++i) {        // f 36..59: tau2
                float a = __log2f(1.f + fmaxf(tau02[2*i][1],   0.f));
                float b = __log2f(1.f + fmaxf(tau02[2*i+1][1], 0.f));
                pk[18 + i] = f2bf(a) | (f2bf(b) << 16);
            }
            pk[30] = 0u; pk[31] = 0u;             // f 60..63: pad (W' columns zero)
            uint32_t* dst = (uint32_t*)&featS[p0 * KPE + cl * FPC];   // 16B-aligned
            #pragma unroll
            for (int i = 0; i < FPC / 2; i += 4) {
                u32x4 v; v[0] = pk[i]; v[1] = pk[i+1]; v[2] = pk[i+2]; v[3] = pk[i+3];
                *(u32x4*)(dst + i) = v;
            }
        }

        // grab next item; visible to all threads after the (required) barrier
        if (tid == 0) sIdx = atomicAdd(qcnt, 1u);
        __syncthreads();                  // featS ready + sIdx published
        const unsigned nitem = sIdx;
        const bool have_next = (nitem < NITEMS);

        // ---- prefetch next item's x into registers: overlaps phase B + epilogue ----
        float xn[NG];
        if (have_next) {
            tile  = nitem % NTILES;
            stage = nitem / NTILES;
            bb  = tile / TILES_PER_B;
            psp = (tile - bb * TILES_PER_B) * TP;
            const unsigned nidx0 = (bb * NCH + stage * CHS + (unsigned)cl) * (NG * DHW)
                                 + (psp + (unsigned)p0);
            #pragma unroll
            for (int g = 0; g < NG; ++g) xn[g] = x[nidx0 + (unsigned)(g * DHW)];
        }

        // ---- phase B: wave w accumulates k-steps [8w, 8w+8) for ALL 4 o-tiles ----
        f32x4 accA = {0.f, 0.f, 0.f, 0.f};
        f32x4 accB = {0.f, 0.f, 0.f, 0.f};
        f32x4 accC = {0.f, 0.f, 0.f, 0.f};
        f32x4 accD = {0.f, 0.f, 0.f, 0.f};
        {
            const unsigned kb = cur_stage * KPSTG + (unsigned)(w * KQ);   // global k-step
            const unsigned short* fb = &featS[ln * KPE + (w * KQ) * 32 + lh * 8];
            const s16x8* wb = (const s16x8*)WbS;

            s16x8 bc = *(const s16x8*)(fb);          // b prefetch (shared by 4 o-tiles)
            #pragma unroll
            for (int kk = 0; kk < KQ; ++kk) {
                s16x8 bn = bc;
                if (kk + 1 < KQ) bn = *(const s16x8*)(fb + (kk + 1) * 32);
                const unsigned ai = (kb + (unsigned)kk) * 64u + (unsigned)l;
                s16x8 a0 = wb[ai];
                s16x8 a1 = wb[ai + 1u * KS2 * 64u];
                s16x8 a2 = wb[ai + 2u * KS2 * 64u];
                s16x8 a3 = wb[ai + 3u * KS2 * 64u];
                accA = __builtin_amdgcn_mfma_f32_16x16x32_bf16(a0, bc, accA, 0, 0, 0);
                accB = __builtin_amdgcn_mfma_f32_16x16x32_bf16(a1, bc, accB, 0, 0, 0);
                accC = __builtin_amdgcn_mfma_f32_16x16x32_bf16(a2, bc, accC, 0, 0, 0);
                accD = __builtin_amdgcn_mfma_f32_16x16x32_bf16(a3, bc, accD, 0, 0, 0);
                bc = bn;
            }
        }
        __syncthreads();   // all ds_reads done before redS overlay

        // ---- epilogue: cross-wave k-reduction (featS overlay), atomic o-tile w ----
        {
            f32x4* redS = (f32x4*)featS;      // 4 waves x 4 o-tiles x 64 lanes x 16B
            redS[(w * 4 + 0) * 64 + l] = accA;
            redS[(w * 4 + 1) * 64 + l] = accB;
            redS[(w * 4 + 2) * 64 + l] = accC;
            redS[(w * 4 + 3) * 64 + l] = accD;
            __syncthreads();
            f32x4 r = redS[(0 * 4 + w) * 64 + l] + redS[(1 * 4 + w) * 64 + l]
                    + redS[(2 * 4 + w) * 64 + l] + redS[(3 * 4 + w) * 64 + l];

            const size_t obase = (size_t)cur_bb * NHEAD * DHW + (size_t)(cur_psp + ln);
            #pragma unroll
            for (int j = 0; j < 4; ++j) {
                const int o = w * 16 + lh * 4 + j;
                atomicAdd(&y[obase + (size_t)o * DHW], r[j]);
            }
        }
        __syncthreads();   // redS reads done before featS reuse next iteration

        if (!have_next) break;            // block-uniform
        #pragma unroll
        for (int g = 0; g < NG; ++g) xf[g] = xn[g];
    }
}

extern "C" void kernel_launch(void* const* d_in, const int* in_sizes, int n_in,
                              void* d_out, int out_size, void* d_ws, size_t ws_size,
                              hipStream_t stream) {
    const float* x    = (const float*)d_in[0];
    const float* W    = (const float*)d_in[1];
    const float* bias = (const float*)d_in[2];
    unsigned short* WbS = (unsigned short*)d_ws;            // 262,144 B used
    unsigned* qcnt = (unsigned*)((char*)d_ws + WS_WBS);     // work-queue counter
    float* y = (float*)d_out;

    init_all<<<dim3(PREPB + FILLB), dim3(256), 0, stream>>>(W, WbS, bias, y, qcnt);
    bispec_fused<<<dim3(GRIDP), dim3(256), 0, stream>>>(x, WbS, y, qcnt);
}

// Round 20
// 57.448 us; speedup vs baseline: 1.3194x; 1.3194x over previous
//
#include <hip/hip_runtime.h>
#include <stdint.h>

// ---- problem constants ----
#define DHW         13824      // 24*24*24 spatial positions per (b,c,g) plane
#define NCH         32         // channels C
#define NG          24         // octahedral group order
#define KDIM        2304       // ORIGINAL GEMM K (32 ch * 72)
#define NHEAD       64
#define TP          16         // spatial positions per block
#define CHS         16         // channels per stage (2 stages)
#define FPC         64         // folded+padded features/channel (60 distinct + 4 pad)
#define KP2         2048       // padded folded K: 2 stages x 16 ch x 64
#define KS2         64         // padded K-steps total (KP2/32)
#define KPSTG       32         // K-steps per stage
#define KQ          8          // K-steps per wave per stage (32/4, exact)
#define KPE         1032       // LDS row pitch in bf16 elems (16*64 + 8 pad -> 4-bank skew)
#define TILES_PER_B 864        // DHW / TP
#define NTILES      1728       // B * TILES_PER_B
#define OUTN        1769472    // B * NHEAD * DHW  (output floats)
#define PREPB       512        // init_all blocks doing prep_w work (131072/256)
#define FILLB       1728       // init_all blocks doing bias_fill work (OUTN/4/256)

typedef __attribute__((ext_vector_type(2))) float    f32x2;
typedef __attribute__((ext_vector_type(8))) short    s16x8;
typedef __attribute__((ext_vector_type(4))) float    f32x4;
typedef __attribute__((ext_vector_type(4))) uint32_t u32x4;

// ---- compile-time Cayley table of S4 (matches itertools.permutations order) ----
// t1-fold extras: t1h[h] = t1*h, rep[12] = representatives of tau1[h]==tau1[t1*h].
struct Tables { int cay[NG][NG]; int s1[NG]; int s2[NG]; int t1h[NG]; int rep[12]; };

constexpr Tables make_tables() {
    int perms[NG][4] = {};
    int n = 0;
    for (int a = 0; a < 4; ++a)
        for (int b = 0; b < 4; ++b) {
            if (b == a) continue;
            for (int c = 0; c < 4; ++c) {
                if (c == a || c == b) continue;
                int d = 6 - a - b - c;
                perms[n][0] = a; perms[n][1] = b; perms[n][2] = c; perms[n][3] = d;
                ++n;
            }
        }
    int si1 = 0, si2 = 0;
    for (int i = 0; i < NG; ++i) {
        if (perms[i][0] == 1 && perms[i][1] == 0 && perms[i][2] == 2 && perms[i][3] == 3) si1 = i;
        if (perms[i][0] == 1 && perms[i][1] == 2 && perms[i][2] == 3 && perms[i][3] == 0) si2 = i;
    }
    Tables t{};
    for (int p = 0; p < NG; ++p) {
        for (int q = 0; q < NG; ++q) {
            int c0 = perms[p][perms[q][0]];
            int c1 = perms[p][perms[q][1]];
            int c2 = perms[p][perms[q][2]];
            int c3 = perms[p][perms[q][3]];
            int r = 0;
            for (int i = 0; i < NG; ++i)
                if (perms[i][0] == c0 && perms[i][1] == c1 &&
                    perms[i][2] == c2 && perms[i][3] == c3) { r = i; break; }
            t.cay[p][q] = r;
        }
        t.s1[p] = t.cay[p][si1];
        t.s2[p] = t.cay[p][si2];
    }
    for (int h = 0; h < NG; ++h) t.t1h[h] = t.cay[si1][h];   // t1 o h
    int nr = 0;
    for (int h = 0; h < NG; ++h) if (h < t.t1h[h]) t.rep[nr++] = h;   // 12 pairs
    return t;
}
constexpr Tables TAB = make_tables();

__device__ __forceinline__ uint32_t f2bf(float f) {   // fp32 -> bf16 (RNE), u16 in low bits
    uint32_t u = __float_as_uint(f);
    u += 0x7fffu + ((u >> 16) & 1u);
    return u >> 16;
}

// ---- kernel 1: merged init -- blocks [0,PREPB) fold+swizzle W; blocks [PREPB,..)
// pre-fill y with the bias pattern. The two jobs are independent (different in/out);
// merging removes one dispatch boundary. Branch is block-uniform -> no divergence.
// Folded feature order per channel: [0,24): tau0 | [24,36): tau1 reps (pair-summed W) |
// [36,60): tau2 | [60,64): zero pad. ln2 folded in (phase A uses log2).
__global__ __launch_bounds__(256) void init_all(const float* __restrict__ W,
                                                unsigned short* __restrict__ WbS,
                                                const float* __restrict__ bias,
                                                float* __restrict__ y) {
    const int blk = blockIdx.x;
    if (blk < PREPB) {
        int i = blk * 256 + threadIdx.x;             // < 64*2048 = 131072
        int j  = i & 7;
        int t1_ = i >> 3;
        int l  = t1_ & 63;
        int t2_ = t1_ >> 6;
        int kk = t2_ & (KS2 - 1);
        int ot = t2_ >> 6;
        int o = ot * 16 + (l & 15);
        int k = kk * 32 + ((l >> 4) << 3) + j;       // 0..2047 folded-K column
        int stage = k >> 10;                         // 0..1
        int q     = k & 1023;
        int c = stage * CHS + (q >> 6);              // channel
        int f = q & 63;                              // folded feature index
        const float* Wo = W + o * KDIM + c * 72;
        float val = 0.f;
        if (f < 24)      val = Wo[f * 3 + 0];
        else if (f < 36) { int h = TAB.rep[f - 24];
                           val = Wo[h * 3 + 1] + Wo[TAB.t1h[h] * 3 + 1]; }
        else if (f < 60) { int h = f - 36;          val = Wo[h * 3 + 2]; }
        WbS[i] = (unsigned short)f2bf(val * 0.69314718055994531f);
    } else {
        const int i4 = (blk - PREPB) * 256 + threadIdx.x;   // float4 index, OUTN%1024==0
        const float b = bias[((i4 * 4) / DHW) & (NHEAD - 1)];
        f32x4 v; v[0] = b; v[1] = b; v[2] = b; v[3] = b;
        ((f32x4*)y)[i4] = v;
    }
}

// ---- kernel 2: fused bispectrum + log-feature + 64-head GEMM, 16 positions/block.
// CONVERGED STRUCTURE (R18, 57.8 us). 256 threads (4 waves), launch_bounds(256,2)
// (the only healthy allocator surface: R2-R6 512-thr -> 64-VGPR pin + spills; R12
// min-waves=8 -> 32-VGPR panic + 1.6GB scratch; R7/R9/R11/R13+ -> honest 60-92 VGPR,
// zero spill). One (tile, 16-ch stage) per block, static grid 3456 with XCD-chunked
// swizzle (R19 lesson: dynamic work-queue breaks x L3/L2 locality, FETCH 42->70MB,
// -31% perf). t1-folded K=2048 (R14: tau1[h]==tau1[t1*h], 1/6 of work removed).
// K-split phase B (R13: wave w does k-range for ALL 4 o-tiles -> 1 shared ds_read +
// 4 indep MFMA chains). Direct atomicAdd into bias-prefilled y (R17: no partial-plane
// round trip). Measured nulls/regressions: LDS 32K/5-blk (R15 null), h-split+grid
// 6912 (R16 -9%), persistent+prefetch (R19 -31%).
__global__ __launch_bounds__(256, 2)
void bispec_fused(
        const float* __restrict__ x,
        const unsigned short* __restrict__ WbS,
        float* __restrict__ y)            // bias-prefilled output, atomic accumulate
{
    __shared__ alignas(16) unsigned short featS[TP * KPE];   // 33,024 B

    const int bid = blockIdx.x;
    const int NB  = NTILES * 2;
    // XCD-chunked swizzle (NB % 8 == 0); bijection bid -> (tile, stage)
    const int swz   = (bid & 7) * (NB / 8) + (bid >> 3);
    const int tile  = swz % NTILES;
    const int stage = swz / NTILES;
    const int bb  = tile / TILES_PER_B;
    const int psp = (tile - bb * TILES_PER_B) * TP;
    const int tid = threadIdx.x;

    const int p0 = tid & 15;          // position within tile (phase A)
    const int cl = tid >> 4;          // local channel 0..15 (phase A)
    const int w  = tid >> 6;          // wave: k-quarter in phase B, o-tile in epilogue
    const int l  = tid & 63;
    const int ln = l & 15;            // position col (phase B)
    const int lh = l >> 4;            // k sub-block (phase B)

    f32x4 accA = {0.f, 0.f, 0.f, 0.f};   // o-tile 0 (heads  0..15)
    f32x4 accB = {0.f, 0.f, 0.f, 0.f};   // o-tile 1 (heads 16..31)
    f32x4 accC = {0.f, 0.f, 0.f, 0.f};   // o-tile 2 (heads 32..47)
    f32x4 accD = {0.f, 0.f, 0.f, 0.f};   // o-tile 3 (heads 48..63)

    // ---------------- phase A: one full (c,p) row per thread ----------------
    {
        const int c0 = stage * CHS + cl;
        // 32-bit divergent index vs uniform base -> saddr-form global_load_dword
        const unsigned idx0 = (unsigned)(bb * NCH + c0) * (NG * DHW) + (unsigned)(psp + p0);
        float xf[NG];
        #pragma unroll
        for (int g = 0; g < NG; ++g) xf[g] = x[idx0 + (unsigned)(g * DHW)];

        f32x2 tau02[NG];         // (tau0, tau2) packed
        float tau1[12];          // 12 distinct s1 values (t1-fold)
        #pragma unroll
        for (int h = 0; h < NG; ++h) tau02[h] = (f32x2){0.f, 0.f};
        #pragma unroll
        for (int r = 0; r < 12; ++r) tau1[r] = 0.f;
        #pragma unroll
        for (int g = 0; g < NG; ++g) {
            const float xg = xf[g];
            const f32x2 q02 = (f32x2){xg, xg} * (f32x2){xg, xf[TAB.s2[g]]};
            const float q1 = xg * xf[TAB.s1[g]];
            #pragma unroll
            for (int h = 0; h < NG; ++h) {
                const float v = xf[TAB.cay[g][h]];   // static register index
                tau02[h] = __builtin_elementwise_fma((f32x2){v, v}, q02, tau02[h]);
            }
            #pragma unroll
            for (int r = 0; r < 12; ++r) {
                const float v = xf[TAB.cay[g][TAB.rep[r]]];   // static register index
                tau1[r] = fmaf(q1, v, tau1[r]);
            }
        }
        // feature = log2(1 + max(tau,0))  [ln2 folded into W; log2(1)=0 exact]
        uint32_t pk[FPC / 2];
        #pragma unroll
        for (int i = 0; i < 12; ++i) {        // f 0..23: tau0
            float a = __log2f(1.f + fmaxf(tau02[2*i][0],   0.f));
            float b = __log2f(1.f + fmaxf(tau02[2*i+1][0], 0.f));
            pk[i] = f2bf(a) | (f2bf(b) << 16);
        }
        #pragma unroll
        for (int i = 0; i < 6; ++i) {         // f 24..35: tau1 reps
            float a = __log2f(1.f + fmaxf(tau1[2*i],   0.f));
            float b = __log2f(1.f + fmaxf(tau1[2*i+1], 0.f));
            pk[12 + i] = f2bf(a) | (f2bf(b) << 16);
        }
        #pragma unroll
        for (int i = 0; i < 12; ++i) {        // f 36..59: tau2
            float a = __log2f(1.f + fmaxf(tau02[2*i][1],   0.f));
            float b = __log2f(1.f + fmaxf(tau02[2*i+1][1], 0.f));
            pk[18 + i] = f2bf(a) | (f2bf(b) << 16);
        }
        pk[30] = 0u; pk[31] = 0u;             // f 60..63: pad (W' columns are zero)
        // row: p0*2064B (16B-aligned) + cl*128B (16B-aligned) -> 8 x b128 stores
        uint32_t* dst = (uint32_t*)&featS[p0 * KPE + cl * FPC];
        #pragma unroll
        for (int i = 0; i < FPC / 2; i += 4) {
            u32x4 v; v[0] = pk[i]; v[1] = pk[i+1]; v[2] = pk[i+2]; v[3] = pk[i+3];
            *(u32x4*)(dst + i) = v;
        }
    }
    __syncthreads();

    // ---- phase B: wave w accumulates k-steps [8w, 8w+8) for ALL 4 o-tiles ----
    {
        const unsigned kb = (unsigned)(stage * KPSTG + w * KQ);   // global k-step
        const unsigned short* fb = &featS[ln * KPE + (w * KQ) * 32 + lh * 8];
        const s16x8* wb = (const s16x8*)WbS;

        s16x8 bc = *(const s16x8*)(fb);          // b prefetch (shared by 4 o-tiles)
        #pragma unroll
        for (int kk = 0; kk < KQ; ++kk) {
            s16x8 bn = bc;
            if (kk + 1 < KQ) bn = *(const s16x8*)(fb + (kk + 1) * 32);
            const unsigned ai = (kb + (unsigned)kk) * 64u + (unsigned)l;
            s16x8 a0 = wb[ai];
            s16x8 a1 = wb[ai + 1u * KS2 * 64u];
            s16x8 a2 = wb[ai + 2u * KS2 * 64u];
            s16x8 a3 = wb[ai + 3u * KS2 * 64u];
            accA = __builtin_amdgcn_mfma_f32_16x16x32_bf16(a0, bc, accA, 0, 0, 0);
            accB = __builtin_amdgcn_mfma_f32_16x16x32_bf16(a1, bc, accB, 0, 0, 0);
            accC = __builtin_amdgcn_mfma_f32_16x16x32_bf16(a2, bc, accC, 0, 0, 0);
            accD = __builtin_amdgcn_mfma_f32_16x16x32_bf16(a3, bc, accD, 0, 0, 0);
            bc = bn;
        }
    }
    __syncthreads();   // all ds_reads done before redS overlay

    // ---- epilogue: cross-wave k-reduction (featS dead -> overlay), atomic o-tile w ----
    f32x4* redS = (f32x4*)featS;      // 4 waves x 4 o-tiles x 64 lanes x 16B = 16 KB
    redS[(w * 4 + 0) * 64 + l] = accA;
    redS[(w * 4 + 1) * 64 + l] = accB;
    redS[(w * 4 + 2) * 64 + l] = accC;
    redS[(w * 4 + 3) * 64 + l] = accD;
    __syncthreads();
    f32x4 r = redS[(0 * 4 + w) * 64 + l] + redS[(1 * 4 + w) * 64 + l]
            + redS[(2 * 4 + w) * 64 + l] + redS[(3 * 4 + w) * 64 + l];

    // D layout: col = lane&15 (position), row = (lane>>4)*4 + j (head within o-tile w)
    const size_t obase = (size_t)bb * NHEAD * DHW + (size_t)(psp + ln);
    #pragma unroll
    for (int j = 0; j < 4; ++j) {
        const int o = w * 16 + lh * 4 + j;
        atomicAdd(&y[obase + (size_t)o * DHW], r[j]);
    }
}

extern "C" void kernel_launch(void* const* d_in, const int* in_sizes, int n_in,
                              void* d_out, int out_size, void* d_ws, size_t ws_size,
                              hipStream_t stream) {
    const float* x    = (const float*)d_in[0];
    const float* W    = (const float*)d_in[1];
    const float* bias = (const float*)d_in[2];
    unsigned short* WbS = (unsigned short*)d_ws;            // 262,144 B used
    float* y = (float*)d_out;

    init_all<<<dim3(PREPB + FILLB), dim3(256), 0, stream>>>(W, WbS, bias, y);
    bispec_fused<<<dim3(NTILES * 2), dim3(256), 0, stream>>>(x, WbS, y);
}